// Round 1
// baseline (466.112 us; speedup 1.0000x reference)
//
#include <hip/hip_runtime.h>
#include <stdint.h>

typedef unsigned short u16;
typedef u16 u16x4 __attribute__((ext_vector_type(4)));
typedef u16 u16x8 __attribute__((ext_vector_type(8)));
typedef float f32x4 __attribute__((ext_vector_type(4)));
typedef __bf16 bf16x8 __attribute__((ext_vector_type(8)));

#define N_TOK 4096
#define C_DIM 1024
#define E_NUM 8
#define H_DIM 512
#define HS_DIM 2048
#define NPAIR (N_TOK * 2)

__device__ __forceinline__ u16 f2b(float f) {
    uint32_t u = __builtin_bit_cast(uint32_t, f);
    uint32_t r = (u + 0x7FFFu + ((u >> 16) & 1u)) >> 16;
    return (u16)r;
}
__device__ __forceinline__ float b2f(u16 h) {
    uint32_t u = ((uint32_t)h) << 16;
    return __builtin_bit_cast(float, u);
}

// ---------------- fp32 -> bf16 straight convert (vectorized) ----------------
__global__ void k_convert(const float* __restrict__ in, u16* __restrict__ out, int n4) {
    int i = blockIdx.x * blockDim.x + threadIdx.x;
    if (i >= n4) return;
    f32x4 v = ((const f32x4*)in)[i];
    u16x4 o;
    o.x = f2b(v.x); o.y = f2b(v.y); o.z = f2b(v.z); o.w = f2b(v.w);
    ((u16x4*)out)[i] = o;
}

// ---------------- fp32 [Z][R][S] -> bf16 [Z][S][R] transpose convert --------
__global__ void k_convT(const float* __restrict__ in, u16* __restrict__ out, int R, int S) {
    __shared__ float t[32][33];
    int z = blockIdx.z;
    const float* inz = in + (size_t)z * R * S;
    u16* outz = out + (size_t)z * R * S;
    int s0 = blockIdx.x * 32, r0 = blockIdx.y * 32;
    int tx = threadIdx.x, ty = threadIdx.y;
#pragma unroll
    for (int i = 0; i < 4; i++)
        t[ty + 8 * i][tx] = inz[(size_t)(r0 + ty + 8 * i) * S + s0 + tx];
    __syncthreads();
#pragma unroll
    for (int i = 0; i < 4; i++)
        outz[(size_t)(s0 + ty + 8 * i) * R + r0 + tx] = f2b(t[tx][ty + 8 * i]);
}

// ---------------- router: fp32 logits, top-2, sigmoid gates -----------------
__global__ void k_router(const float* __restrict__ x, const float* __restrict__ rw,
                         int* __restrict__ topidx, float* __restrict__ gatev,
                         int* __restrict__ counts) {
    int n = blockIdx.x;
    int lane = threadIdx.x;
    const float* xr = x + (size_t)n * C_DIM;
    float acc[E_NUM];
#pragma unroll
    for (int e = 0; e < E_NUM; e++) acc[e] = 0.f;
    for (int c = lane; c < C_DIM; c += 64) {
        float xv = xr[c];
#pragma unroll
        for (int e = 0; e < E_NUM; e++) acc[e] += xv * rw[e * C_DIM + c];
    }
#pragma unroll
    for (int e = 0; e < E_NUM; e++)
        for (int m = 32; m >= 1; m >>= 1) acc[e] += __shfl_xor(acc[e], m);
    if (lane == 0) {
        int i1 = 0; float v1 = acc[0];
        for (int e = 1; e < E_NUM; e++) if (acc[e] > v1) { v1 = acc[e]; i1 = e; }
        int i2 = -1; float v2 = -1e30f;
        for (int e = 0; e < E_NUM; e++) if (e != i1 && acc[e] > v2) { v2 = acc[e]; i2 = e; }
        float g1 = 1.f / (1.f + __expf(-v1));
        float g2 = 1.f / (1.f + __expf(-v2));
        topidx[n * 2] = i1; topidx[n * 2 + 1] = i2;
        gatev[n * 2] = g1;  gatev[n * 2 + 1] = g2;
        atomicAdd(&counts[i1], 1);
        atomicAdd(&counts[i2], 1);
    }
}

__global__ void k_scan(const int* __restrict__ counts, int* __restrict__ offs,
                       int* __restrict__ cursor) {
    if (threadIdx.x == 0) {
        int o = 0;
        for (int e = 0; e < E_NUM; e++) { offs[e] = o; cursor[e] = o; o += counts[e]; }
        offs[E_NUM] = o;
    }
}

__global__ void k_scatter(const int* __restrict__ topidx, const float* __restrict__ gatev,
                          int* __restrict__ cursor, int* __restrict__ pairlist,
                          float* __restrict__ gate_g) {
    int n = blockIdx.x * blockDim.x + threadIdx.x;
    if (n >= N_TOK) return;
    for (int s = 0; s < 2; s++) {
        int e = topidx[n * 2 + s];
        int pos = atomicAdd(&cursor[e], 1);
        pairlist[pos] = n * 2 + s;
        gate_g[pos] = gatev[n * 2 + s];
    }
}

// ---------------- 128x128 tile bf16 GEMM, C[M,N] = A[M,K] * B'[N,K]^T -------
// 4 waves, each 64x64 quadrant, 16x16x32 MFMA, global_load_lds staging.
template <bool GATHER_A, bool SCATTER_C, bool OUT_BF16, bool ADD_PAIRS>
__global__ __launch_bounds__(256) void k_gemm(
    const u16* __restrict__ A, const u16* __restrict__ B, void* __restrict__ Cout,
    const u16* __restrict__ pairbuf, const int* __restrict__ offs,
    const int* __restrict__ pairlist, int M, int N, int K) {
    int e = blockIdx.z;
    int base = 0, cnt = M;
    if (offs) { base = offs[e]; cnt = offs[e + 1] - base; }
    int m0 = blockIdx.y * 128;
    if (m0 >= cnt) return;
    int n0 = blockIdx.x * 128;
    const u16* Bp = B + (size_t)e * N * K;

    __shared__ __align__(16) u16 lA[128 * 32];
    __shared__ __align__(16) u16 lB[128 * 32];

    int tid = threadIdx.x;
    int w = tid >> 6, lane = tid & 63;
    int wr = w >> 1, wc = w & 1;

    int srow = lane >> 2;          // 0..15 within 16-row group
    int scol = (lane & 3) * 8;     // element col 0..31

    size_t arow_off[2];
#pragma unroll
    for (int i = 0; i < 2; i++) {
        int r = (2 * w + i) * 16 + srow;   // tile row 0..127
        int rr = m0 + r; if (rr > cnt - 1) rr = cnt - 1;
        long grow;
        if (GATHER_A) grow = (long)(pairlist[base + rr] >> 1);
        else          grow = (long)(base + rr);
        arow_off[i] = (size_t)grow * K;
    }

    f32x4 acc[4][4];
#pragma unroll
    for (int i = 0; i < 4; i++)
#pragma unroll
        for (int j = 0; j < 4; j++) acc[i][j] = f32x4{0.f, 0.f, 0.f, 0.f};

    for (int k0 = 0; k0 < K; k0 += 32) {
#pragma unroll
        for (int i = 0; i < 2; i++) {
            int r = (2 * w + i) * 16 + srow;
            const u16* gA = A + arow_off[i] + k0 + scol;
            const u16* gB = Bp + (size_t)(n0 + r) * K + k0 + scol;
            __builtin_amdgcn_global_load_lds(
                (const __attribute__((address_space(1))) void*)gA,
                (__attribute__((address_space(3))) void*)&lA[(2 * w + i) * 16 * 32], 16, 0, 0);
            __builtin_amdgcn_global_load_lds(
                (const __attribute__((address_space(1))) void*)gB,
                (__attribute__((address_space(3))) void*)&lB[(2 * w + i) * 16 * 32], 16, 0, 0);
        }
        __syncthreads();
        bf16x8 af[4], bfr[4];
#pragma unroll
        for (int m = 0; m < 4; m++) {
            int row = wr * 64 + m * 16 + (lane & 15);
            af[m] = *(const bf16x8*)&lA[row * 32 + (lane >> 4) * 8];
        }
#pragma unroll
        for (int n = 0; n < 4; n++) {
            int row = wc * 64 + n * 16 + (lane & 15);
            bfr[n] = *(const bf16x8*)&lB[row * 32 + (lane >> 4) * 8];
        }
#pragma unroll
        for (int m = 0; m < 4; m++)
#pragma unroll
            for (int n = 0; n < 4; n++)
                acc[m][n] = __builtin_amdgcn_mfma_f32_16x16x32_bf16(af[m], bfr[n], acc[m][n], 0, 0, 0);
        __syncthreads();
    }

    // epilogue: D[row=(lane>>4)*4+j][col=lane&15] per fragment
#pragma unroll
    for (int m = 0; m < 4; m++) {
#pragma unroll
        for (int j = 0; j < 4; j++) {
            int rloc = wr * 64 + m * 16 + (lane >> 4) * 4 + j;
            if (m0 + rloc >= cnt) continue;
            long crow;
            if (SCATTER_C) crow = pairlist[base + m0 + rloc];
            else           crow = base + m0 + rloc;
#pragma unroll
            for (int n = 0; n < 4; n++) {
                int col = n0 + wc * 64 + n * 16 + (lane & 15);
                float v = acc[m][n][j];
                if (ADD_PAIRS) {
                    v += b2f(pairbuf[(size_t)(2 * crow) * N + col]) +
                         b2f(pairbuf[(size_t)(2 * crow + 1) * N + col]);
                    ((float*)Cout)[(size_t)crow * N + col] = v;
                } else if (OUT_BF16) {
                    ((u16*)Cout)[(size_t)crow * N + col] = f2b(v);
                } else {
                    ((float*)Cout)[(size_t)crow * N + col] = v;
                }
            }
        }
    }
}

// ---------------- SwiGLU (expert, with gate fold) ---------------------------
__global__ void k_swiglu_e(const u16* __restrict__ gu, const float* __restrict__ gate_g,
                           u16* __restrict__ hid) {
    int i = blockIdx.x * blockDim.x + threadIdx.x;
    if (i >= NPAIR * 64) return;
    int p = i >> 6;
    int h0 = (i & 63) * 8;
    float gs = gate_g[p];
    u16x8 gv = *(const u16x8*)(gu + (size_t)p * 1024 + h0);
    u16x8 uv = *(const u16x8*)(gu + (size_t)p * 1024 + 512 + h0);
    u16x8 ov;
#pragma unroll
    for (int j = 0; j < 8; j++) {
        float g = b2f(gv[j]), u = b2f(uv[j]);
        float s = g / (1.f + __expf(-g));
        ov[j] = f2b(gs * s * u);
    }
    *(u16x8*)(hid + (size_t)p * 512 + h0) = ov;
}

// ---------------- SwiGLU (shared) -------------------------------------------
__global__ void k_swiglu_s(const u16* __restrict__ gu, u16* __restrict__ hid) {
    int i = blockIdx.x * blockDim.x + threadIdx.x;
    if (i >= N_TOK * 256) return;
    int p = i >> 8;
    int h0 = (i & 255) * 8;
    u16x8 gv = *(const u16x8*)(gu + (size_t)p * 4096 + h0);
    u16x8 uv = *(const u16x8*)(gu + (size_t)p * 4096 + 2048 + h0);
    u16x8 ov;
#pragma unroll
    for (int j = 0; j < 8; j++) {
        float g = b2f(gv[j]), u = b2f(uv[j]);
        float s = g / (1.f + __expf(-g));
        ov[j] = f2b(s * u);
    }
    *(u16x8*)(hid + (size_t)p * 2048 + h0) = ov;
}

extern "C" void kernel_launch(void* const* d_in, const int* in_sizes, int n_in,
                              void* d_out, int out_size, void* d_ws, size_t ws_size,
                              hipStream_t stream) {
    const float* x   = (const float*)d_in[0];
    const float* rw  = (const float*)d_in[1];
    const float* guw = (const float*)d_in[2];
    const float* dnw = (const float*)d_in[3];
    const float* sgw = (const float*)d_in[4];
    const float* suw = (const float*)d_in[5];
    const float* sdw = (const float*)d_in[6];
    float* out = (float*)d_out;
    char* ws = (char*)d_ws;

    // ws layout (bytes); sharedgu aliases [w_gu|guout], sharedhid aliases [w_dn|hidden]
    u16* xb        = (u16*)(ws + 0);          //  8 MiB  [4096][1024]
    u16* w_gu      = (u16*)(ws + 8388608);    // 16 MiB  [8][1024][1024] (B' = gate_up^T)
    u16* guout     = (u16*)(ws + 25165824);   // 16 MiB  [8192][1024]
    u16* sharedgu  = (u16*)(ws + 8388608);    // 32 MiB  [4096][4096]  (alias, used later)
    u16* w_dn      = (u16*)(ws + 41943040);   //  8 MiB  [8][1024][512] (B' = down^T)
    u16* hidden    = (u16*)(ws + 50331648);   //  8 MiB  [8192][512]
    u16* sharedhid = (u16*)(ws + 41943040);   // 16 MiB  [4096][2048]  (alias, used later)
    u16* w_sgu     = (u16*)(ws + 58720256);   //  8 MiB  [4096][1024] (sg rows then su rows)
    u16* w_sd      = (u16*)(ws + 67108864);   //  4 MiB  [1024][2048]
    u16* pairout   = (u16*)(ws + 71303168);   // 16 MiB  [8192][1024]
    int*   topidx   = (int*)(ws + 88080384);
    float* gatev    = (float*)(ws + 88080384 + 32768);
    int*   pairlist = (int*)(ws + 88080384 + 65536);
    float* gate_g   = (float*)(ws + 88080384 + 98304);
    int*   counts   = (int*)(ws + 88080384 + 131072);
    int*   offs     = counts + 8;
    int*   cursor   = offs + 9;

    hipMemsetAsync(counts, 0, 128, stream);

    // dtype conversions
    k_convert<<<4096, 256, 0, stream>>>(x, xb, 1048576);
    k_convert<<<2048, 256, 0, stream>>>(sgw, w_sgu, 524288);
    k_convert<<<2048, 256, 0, stream>>>(suw, w_sgu + 2048 * 1024, 524288);
    k_convert<<<2048, 256, 0, stream>>>(sdw, w_sd, 524288);
    dim3 tb(32, 8);
    k_convT<<<dim3(32, 32, 8), tb, 0, stream>>>(guw, w_gu, 1024, 1024);
    k_convT<<<dim3(32, 16, 8), tb, 0, stream>>>(dnw, w_dn, 512, 1024);

    // routing
    k_router<<<4096, 64, 0, stream>>>(x, rw, topidx, gatev, counts);
    k_scan<<<1, 64, 0, stream>>>(counts, offs, cursor);
    k_scatter<<<16, 256, 0, stream>>>(topidx, gatev, cursor, pairlist, gate_g);

    // expert MLP (grouped GEMMs over gathered pairs)
    k_gemm<true, false, true, false><<<dim3(8, 32, 8), 256, 0, stream>>>(
        xb, w_gu, guout, nullptr, offs, pairlist, 0, 1024, 1024);
    k_swiglu_e<<<2048, 256, 0, stream>>>(guout, gate_g, hidden);
    k_gemm<false, true, true, false><<<dim3(8, 32, 8), 256, 0, stream>>>(
        hidden, w_dn, pairout, nullptr, offs, pairlist, 0, 1024, 512);

    // shared expert (sharedgu overwrites w_gu|guout which are now dead)
    k_gemm<false, false, true, false><<<dim3(32, 32, 1), 256, 0, stream>>>(
        xb, w_sgu, sharedgu, nullptr, nullptr, nullptr, 4096, 4096, 1024);
    k_swiglu_s<<<4096, 256, 0, stream>>>(sharedgu, sharedhid);
    // shared down with fused epilogue: out = shared + pair0 + pair1
    k_gemm<false, false, false, true><<<dim3(8, 32, 1), 256, 0, stream>>>(
        sharedhid, w_sd, out, pairout, nullptr, nullptr, 4096, 1024, 2048);
}

// Round 2
// 339.205 us; speedup vs baseline: 1.3741x; 1.3741x over previous
//
#include <hip/hip_runtime.h>
#include <stdint.h>

typedef unsigned short u16;
typedef u16 u16x4 __attribute__((ext_vector_type(4)));
typedef u16 u16x8 __attribute__((ext_vector_type(8)));
typedef float f32x4 __attribute__((ext_vector_type(4)));
typedef __bf16 bf16x8 __attribute__((ext_vector_type(8)));

#define N_TOK 4096
#define C_DIM 1024
#define E_NUM 8
#define H_DIM 512
#define HS_DIM 2048
#define NPAIR (N_TOK * 2)

__device__ __forceinline__ u16 f2b(float f) {
    uint32_t u = __builtin_bit_cast(uint32_t, f);
    uint32_t r = (u + 0x7FFFu + ((u >> 16) & 1u)) >> 16;
    return (u16)r;
}
__device__ __forceinline__ float b2f(u16 h) {
    uint32_t u = ((uint32_t)h) << 16;
    return __builtin_bit_cast(float, u);
}

// ---------------- fp32 -> bf16 straight convert (vectorized) ----------------
__global__ void k_convert(const float* __restrict__ in, u16* __restrict__ out, int n4) {
    int i = blockIdx.x * blockDim.x + threadIdx.x;
    if (i >= n4) return;
    f32x4 v = ((const f32x4*)in)[i];
    u16x4 o;
    o.x = f2b(v.x); o.y = f2b(v.y); o.z = f2b(v.z); o.w = f2b(v.w);
    ((u16x4*)out)[i] = o;
}

// ---------------- fp32 [Z][R][S] -> bf16 [Z][S][R] transpose convert --------
__global__ void k_convT(const float* __restrict__ in, u16* __restrict__ out, int R, int S) {
    __shared__ float t[32][33];
    int z = blockIdx.z;
    const float* inz = in + (size_t)z * R * S;
    u16* outz = out + (size_t)z * R * S;
    int s0 = blockIdx.x * 32, r0 = blockIdx.y * 32;
    int tx = threadIdx.x, ty = threadIdx.y;
#pragma unroll
    for (int i = 0; i < 4; i++)
        t[ty + 8 * i][tx] = inz[(size_t)(r0 + ty + 8 * i) * S + s0 + tx];
    __syncthreads();
#pragma unroll
    for (int i = 0; i < 4; i++)
        outz[(size_t)(s0 + ty + 8 * i) * R + r0 + tx] = f2b(t[tx][ty + 8 * i]);
}

// ---------------- router: fp32 logits, top-2, sigmoid gates -----------------
// 256 blocks x 256 threads; router_w staged in LDS; NO global atomics.
__global__ __launch_bounds__(256) void k_router(const float* __restrict__ x,
                                                const float* __restrict__ rw,
                                                int* __restrict__ topidx,
                                                float* __restrict__ gatev) {
    __shared__ float srw[E_NUM * C_DIM];  // 32 KiB
    int tid = threadIdx.x;
#pragma unroll
    for (int i = 0; i < E_NUM * C_DIM / 4 / 256; i++)
        ((f32x4*)srw)[tid + 256 * i] = ((const f32x4*)rw)[tid + 256 * i];
    __syncthreads();

    int wave = tid >> 6, lane = tid & 63;
    int wid = blockIdx.x * 4 + wave;  // 0..1023
#pragma unroll
    for (int it = 0; it < 4; it++) {
        int n = wid + 1024 * it;
        const f32x4* xr = (const f32x4*)(x + (size_t)n * C_DIM);
        float acc[E_NUM];
#pragma unroll
        for (int e = 0; e < E_NUM; e++) acc[e] = 0.f;
#pragma unroll
        for (int c4 = 0; c4 < 4; c4++) {
            int idx = lane + 64 * c4;
            f32x4 xv = xr[idx];
#pragma unroll
            for (int e = 0; e < E_NUM; e++) {
                f32x4 wv = ((const f32x4*)srw)[e * 256 + idx];
                acc[e] += xv.x * wv.x + xv.y * wv.y + xv.z * wv.z + xv.w * wv.w;
            }
        }
#pragma unroll
        for (int e = 0; e < E_NUM; e++)
#pragma unroll
            for (int m = 32; m >= 1; m >>= 1) acc[e] += __shfl_xor(acc[e], m);
        if (lane == 0) {
            int i1 = 0; float v1 = acc[0];
#pragma unroll
            for (int e = 1; e < E_NUM; e++) if (acc[e] > v1) { v1 = acc[e]; i1 = e; }
            int i2 = -1; float v2 = -1e30f;
#pragma unroll
            for (int e = 0; e < E_NUM; e++) if (e != i1 && acc[e] > v2) { v2 = acc[e]; i2 = e; }
            topidx[n * 2] = i1; topidx[n * 2 + 1] = i2;
            gatev[n * 2] = 1.f / (1.f + __expf(-v1));
            gatev[n * 2 + 1] = 1.f / (1.f + __expf(-v2));
        }
    }
}

// ---------------- build: histogram + scan + deterministic scatter -----------
// ONE block, 1024 threads (16 waves). No global atomics anywhere.
__global__ __launch_bounds__(1024) void k_build(const int* __restrict__ topidx,
                                                const float* __restrict__ gatev,
                                                int* __restrict__ offs,
                                                int* __restrict__ pairlist,
                                                float* __restrict__ gate_g) {
    __shared__ int wcnt[16][E_NUM];
    __shared__ int wbase[16][E_NUM];
    int tid = threadIdx.x, wave = tid >> 6, lane = tid & 63;

    // pass 1: per-wave counts via ballot
    int cnt[E_NUM];
#pragma unroll
    for (int e = 0; e < E_NUM; e++) cnt[e] = 0;
#pragma unroll
    for (int i = 0; i < 8; i++) {
        int idx = topidx[wave * 512 + i * 64 + lane];
#pragma unroll
        for (int e = 0; e < E_NUM; e++) {
            unsigned long long m = __ballot(idx == e);
            cnt[e] += __popcll(m);
        }
    }
    if (lane == 0)
#pragma unroll
        for (int e = 0; e < E_NUM; e++) wcnt[wave][e] = cnt[e];
    __syncthreads();

    // scan (serial on thread 0 — 16x8 elements, trivial)
    if (tid == 0) {
        int o = 0;
        for (int e = 0; e < E_NUM; e++) {
            offs[e] = o;
            int r = o;
            for (int w = 0; w < 16; w++) { wbase[w][e] = r; r += wcnt[w][e]; }
            o = r;
        }
        offs[E_NUM] = o;
    }
    __syncthreads();

    // pass 2: deterministic ballot-rank scatter
    int run[E_NUM];
#pragma unroll
    for (int e = 0; e < E_NUM; e++) run[e] = wbase[wave][e];
#pragma unroll
    for (int i = 0; i < 8; i++) {
        int gi = wave * 512 + i * 64 + lane;
        int idx = topidx[gi];
        float gv = gatev[gi];
        int pos = 0;
#pragma unroll
        for (int e = 0; e < E_NUM; e++) {
            unsigned long long m = __ballot(idx == e);
            unsigned long long below = m & ((1ull << lane) - 1ull);
            if (idx == e) pos = run[e] + __popcll(below);
            run[e] += __popcll(m);
        }
        pairlist[pos] = gi;
        gate_g[pos] = gv;
    }
}

// ---------------- 128x128 tile bf16 GEMM, C[M,N] = A[M,K] * B'[N,K]^T -------
// 4 waves, each 64x64 quadrant, 16x16x32 MFMA, global_load_lds staging.
template <bool GATHER_A, bool SCATTER_C, bool OUT_BF16, bool ADD_PAIRS>
__global__ __launch_bounds__(256) void k_gemm(
    const u16* __restrict__ A, const u16* __restrict__ B, void* __restrict__ Cout,
    const u16* __restrict__ pairbuf, const int* __restrict__ offs,
    const int* __restrict__ pairlist, int M, int N, int K) {
    int e = blockIdx.z;
    int base = 0, cnt = M;
    if (offs) { base = offs[e]; cnt = offs[e + 1] - base; }
    int m0 = blockIdx.y * 128;
    if (m0 >= cnt) return;
    int n0 = blockIdx.x * 128;
    const u16* Bp = B + (size_t)e * N * K;

    __shared__ __align__(16) u16 lA[128 * 32];
    __shared__ __align__(16) u16 lB[128 * 32];

    int tid = threadIdx.x;
    int w = tid >> 6, lane = tid & 63;
    int wr = w >> 1, wc = w & 1;

    int srow = lane >> 2;          // 0..15 within 16-row group
    int scol = (lane & 3) * 8;     // element col 0..31

    size_t arow_off[2];
#pragma unroll
    for (int i = 0; i < 2; i++) {
        int r = (2 * w + i) * 16 + srow;   // tile row 0..127
        int rr = m0 + r; if (rr > cnt - 1) rr = cnt - 1;
        long grow;
        if (GATHER_A) grow = (long)(pairlist[base + rr] >> 1);
        else          grow = (long)(base + rr);
        arow_off[i] = (size_t)grow * K;
    }

    f32x4 acc[4][4];
#pragma unroll
    for (int i = 0; i < 4; i++)
#pragma unroll
        for (int j = 0; j < 4; j++) acc[i][j] = f32x4{0.f, 0.f, 0.f, 0.f};

    for (int k0 = 0; k0 < K; k0 += 32) {
#pragma unroll
        for (int i = 0; i < 2; i++) {
            int r = (2 * w + i) * 16 + srow;
            const u16* gA = A + arow_off[i] + k0 + scol;
            const u16* gB = Bp + (size_t)(n0 + r) * K + k0 + scol;
            __builtin_amdgcn_global_load_lds(
                (const __attribute__((address_space(1))) void*)gA,
                (__attribute__((address_space(3))) void*)&lA[(2 * w + i) * 16 * 32], 16, 0, 0);
            __builtin_amdgcn_global_load_lds(
                (const __attribute__((address_space(1))) void*)gB,
                (__attribute__((address_space(3))) void*)&lB[(2 * w + i) * 16 * 32], 16, 0, 0);
        }
        __syncthreads();
        bf16x8 af[4], bfr[4];
#pragma unroll
        for (int m = 0; m < 4; m++) {
            int row = wr * 64 + m * 16 + (lane & 15);
            af[m] = *(const bf16x8*)&lA[row * 32 + (lane >> 4) * 8];
        }
#pragma unroll
        for (int n = 0; n < 4; n++) {
            int row = wc * 64 + n * 16 + (lane & 15);
            bfr[n] = *(const bf16x8*)&lB[row * 32 + (lane >> 4) * 8];
        }
#pragma unroll
        for (int m = 0; m < 4; m++)
#pragma unroll
            for (int n = 0; n < 4; n++)
                acc[m][n] = __builtin_amdgcn_mfma_f32_16x16x32_bf16(af[m], bfr[n], acc[m][n], 0, 0, 0);
        __syncthreads();
    }

    // epilogue: D[row=(lane>>4)*4+j][col=lane&15] per fragment
#pragma unroll
    for (int m = 0; m < 4; m++) {
#pragma unroll
        for (int j = 0; j < 4; j++) {
            int rloc = wr * 64 + m * 16 + (lane >> 4) * 4 + j;
            if (m0 + rloc >= cnt) continue;
            long crow;
            if (SCATTER_C) crow = pairlist[base + m0 + rloc];
            else           crow = base + m0 + rloc;
#pragma unroll
            for (int n = 0; n < 4; n++) {
                int col = n0 + wc * 64 + n * 16 + (lane & 15);
                float v = acc[m][n][j];
                if (ADD_PAIRS) {
                    v += b2f(pairbuf[(size_t)(2 * crow) * N + col]) +
                         b2f(pairbuf[(size_t)(2 * crow + 1) * N + col]);
                    ((float*)Cout)[(size_t)crow * N + col] = v;
                } else if (OUT_BF16) {
                    ((u16*)Cout)[(size_t)crow * N + col] = f2b(v);
                } else {
                    ((float*)Cout)[(size_t)crow * N + col] = v;
                }
            }
        }
    }
}

// ---------------- SwiGLU (expert, with gate fold) ---------------------------
__global__ void k_swiglu_e(const u16* __restrict__ gu, const float* __restrict__ gate_g,
                           u16* __restrict__ hid) {
    int i = blockIdx.x * blockDim.x + threadIdx.x;
    if (i >= NPAIR * 64) return;
    int p = i >> 6;
    int h0 = (i & 63) * 8;
    float gs = gate_g[p];
    u16x8 gv = *(const u16x8*)(gu + (size_t)p * 1024 + h0);
    u16x8 uv = *(const u16x8*)(gu + (size_t)p * 1024 + 512 + h0);
    u16x8 ov;
#pragma unroll
    for (int j = 0; j < 8; j++) {
        float g = b2f(gv[j]), u = b2f(uv[j]);
        float s = g / (1.f + __expf(-g));
        ov[j] = f2b(gs * s * u);
    }
    *(u16x8*)(hid + (size_t)p * 512 + h0) = ov;
}

// ---------------- SwiGLU (shared) -------------------------------------------
__global__ void k_swiglu_s(const u16* __restrict__ gu, u16* __restrict__ hid) {
    int i = blockIdx.x * blockDim.x + threadIdx.x;
    if (i >= N_TOK * 256) return;
    int p = i >> 8;
    int h0 = (i & 255) * 8;
    u16x8 gv = *(const u16x8*)(gu + (size_t)p * 4096 + h0);
    u16x8 uv = *(const u16x8*)(gu + (size_t)p * 4096 + 2048 + h0);
    u16x8 ov;
#pragma unroll
    for (int j = 0; j < 8; j++) {
        float g = b2f(gv[j]), u = b2f(uv[j]);
        float s = g / (1.f + __expf(-g));
        ov[j] = f2b(s * u);
    }
    *(u16x8*)(hid + (size_t)p * 2048 + h0) = ov;
}

extern "C" void kernel_launch(void* const* d_in, const int* in_sizes, int n_in,
                              void* d_out, int out_size, void* d_ws, size_t ws_size,
                              hipStream_t stream) {
    const float* x   = (const float*)d_in[0];
    const float* rw  = (const float*)d_in[1];
    const float* guw = (const float*)d_in[2];
    const float* dnw = (const float*)d_in[3];
    const float* sgw = (const float*)d_in[4];
    const float* suw = (const float*)d_in[5];
    const float* sdw = (const float*)d_in[6];
    float* out = (float*)d_out;
    char* ws = (char*)d_ws;

    // ws layout (bytes); sharedgu aliases [w_gu|guout], sharedhid aliases [w_dn|hidden]
    u16* xb        = (u16*)(ws + 0);          //  8 MiB  [4096][1024]
    u16* w_gu      = (u16*)(ws + 8388608);    // 16 MiB  [8][1024][1024] (B' = gate_up^T)
    u16* guout     = (u16*)(ws + 25165824);   // 16 MiB  [8192][1024]
    u16* sharedgu  = (u16*)(ws + 8388608);    // 32 MiB  [4096][4096]  (alias, used later)
    u16* w_dn      = (u16*)(ws + 41943040);   //  8 MiB  [8][1024][512] (B' = down^T)
    u16* hidden    = (u16*)(ws + 50331648);   //  8 MiB  [8192][512]
    u16* sharedhid = (u16*)(ws + 41943040);   // 16 MiB  [4096][2048]  (alias, used later)
    u16* w_sgu     = (u16*)(ws + 58720256);   //  8 MiB  [4096][1024] (sg rows then su rows)
    u16* w_sd      = (u16*)(ws + 67108864);   //  4 MiB  [1024][2048]
    u16* pairout   = (u16*)(ws + 71303168);   // 16 MiB  [8192][1024]
    int*   topidx   = (int*)(ws + 88080384);
    float* gatev    = (float*)(ws + 88080384 + 32768);
    int*   pairlist = (int*)(ws + 88080384 + 65536);
    float* gate_g   = (float*)(ws + 88080384 + 98304);
    int*   offs     = (int*)(ws + 88080384 + 131072);

    // dtype conversions
    k_convert<<<4096, 256, 0, stream>>>(x, xb, 1048576);
    k_convert<<<2048, 256, 0, stream>>>(sgw, w_sgu, 524288);
    k_convert<<<2048, 256, 0, stream>>>(suw, w_sgu + 2048 * 1024, 524288);
    k_convert<<<2048, 256, 0, stream>>>(sdw, w_sd, 524288);
    dim3 tb(32, 8);
    k_convT<<<dim3(32, 32, 8), tb, 0, stream>>>(guw, w_gu, 1024, 1024);
    k_convT<<<dim3(32, 16, 8), tb, 0, stream>>>(dnw, w_dn, 512, 1024);

    // routing (atomic-free)
    k_router<<<256, 256, 0, stream>>>(x, rw, topidx, gatev);
    k_build<<<1, 1024, 0, stream>>>(topidx, gatev, offs, pairlist, gate_g);

    // expert MLP (grouped GEMMs over gathered pairs)
    k_gemm<true, false, true, false><<<dim3(8, 32, 8), 256, 0, stream>>>(
        xb, w_gu, guout, nullptr, offs, pairlist, 0, 1024, 1024);
    k_swiglu_e<<<2048, 256, 0, stream>>>(guout, gate_g, hidden);
    k_gemm<false, true, true, false><<<dim3(8, 32, 8), 256, 0, stream>>>(
        hidden, w_dn, pairout, nullptr, offs, pairlist, 0, 1024, 512);

    // shared expert (sharedgu overwrites w_gu|guout which are now dead)
    k_gemm<false, false, true, false><<<dim3(32, 32, 1), 256, 0, stream>>>(
        xb, w_sgu, sharedgu, nullptr, nullptr, nullptr, 4096, 4096, 1024);
    k_swiglu_s<<<4096, 256, 0, stream>>>(sharedgu, sharedhid);
    // shared down with fused epilogue: out = shared + pair0 + pair1
    k_gemm<false, false, false, true><<<dim3(8, 32, 1), 256, 0, stream>>>(
        sharedhid, w_sd, out, pairout, nullptr, nullptr, 4096, 1024, 2048);
}